// Round 11
// baseline (221.302 us; speedup 1.0000x reference)
//
#include <hip/hip_runtime.h>
#include <math.h>

// B=4, N=256, D=256, H=8, DK=32, DV=32, R=64
constexpr int B_ = 4, N_ = 256, D_ = 256, H_ = 8, DK_ = 32, DV_ = 32, R_ = 64;
constexpr float SCALE_ = 0.17677669529663687f;  // 1/sqrt(32)
constexpr float EPS_ = 1e-6f;

// ---------------------------------------------------------------------------
// K1: Ek = relationE @ Wr, Ev = relationE @ Wvv   ([64,256] @ [256,256])
__global__ __launch_bounds__(256) void ekev_kernel(
        const float* __restrict__ relE, const float* __restrict__ Wr,
        const float* __restrict__ Wvv, float* __restrict__ Ek,
        float* __restrict__ Ev) {
    int r = blockIdx.x & 63;
    int which = blockIdx.x >> 6;
    const float* W = which ? Wvv : Wr;
    float* out = which ? Ev : Ek;
    __shared__ float row[256];
    int tid = threadIdx.x;
    row[tid] = relE[r * 256 + tid];
    __syncthreads();
    float acc = 0.f;
    for (int d = 0; d < 256; ++d) acc += row[d] * W[d * 256 + tid];
    out[r * 256 + tid] = acc;
}

// ---------------------------------------------------------------------------
// K2: Mcat[d, h*64+r] = sum_dk Wq[d, h*32+dk] * Ek[r, h*32+dk]
__global__ __launch_bounds__(256) void mcat_kernel(
        const float* __restrict__ Wq, const float* __restrict__ Ek,
        float* __restrict__ M) {
    int d = blockIdx.x;
    int t = threadIdx.x;
    __shared__ float wrow[256];
    wrow[t] = Wq[d * 256 + t];
    __syncthreads();
    for (int hr = t; hr < 512; hr += 256) {
        int h = hr >> 6, r = hr & 63;
        const float4* ek4 = (const float4*)(Ek + r * 256 + h * 32);
        const float4* w4 = (const float4*)(wrow + h * 32);
        float acc = 0.f;
#pragma unroll
        for (int k = 0; k < 8; ++k) {
            float4 e = ek4[k], w = w4[k];
            acc += e.x * w.x + e.y * w.y + e.z * w.z + e.w * w.w;
        }
        M[d * 512 + hr] = acc;
    }
}

// ---------------------------------------------------------------------------
// K3: fused projection GEMM: [1024 x 1280] = q[1024,256] @ cat(Wq,Wk,Wv,Mcat)
// 64x64 tile, 16x16 threads, 4x4 acc. grid = 20*16 = 320.
__global__ __launch_bounds__(256) void projT_kernel(
        const float* __restrict__ q, const float* __restrict__ Wq,
        const float* __restrict__ Wk, const float* __restrict__ Wv,
        const float* __restrict__ M, float* __restrict__ Xq,
        float* __restrict__ Xk, float* __restrict__ Xv,
        float* __restrict__ T) {
    int ct = blockIdx.x >> 4, rt = blockIdx.x & 15;
    int t = threadIdx.x;
    __shared__ float ash[32 * 65];
    __shared__ float bsh[32 * 64];
    const float* W;
    int ncols, cbase;
    if (ct < 4)       { W = Wq; cbase = ct * 64;        ncols = 256; }
    else if (ct < 8)  { W = Wk; cbase = (ct - 4) * 64;  ncols = 256; }
    else if (ct < 12) { W = Wv; cbase = (ct - 8) * 64;  ncols = 256; }
    else              { W = M;  cbase = (ct - 12) * 64; ncols = 512; }
    int ti = t >> 4, tj = t & 15;
    float acc[4][4] = {{0.f}};
    for (int kc = 0; kc < 8; ++kc) {
        __syncthreads();
#pragma unroll
        for (int kk = 0; kk < 2; ++kk) {
            int m = t + kk * 256;
            int i = m >> 3, kq = m & 7;
            float4 v = *(const float4*)(q + (size_t)(rt * 64 + i) * 256 + kc * 32 + kq * 4);
            ash[(kq * 4 + 0) * 65 + i] = v.x;
            ash[(kq * 4 + 1) * 65 + i] = v.y;
            ash[(kq * 4 + 2) * 65 + i] = v.z;
            ash[(kq * 4 + 3) * 65 + i] = v.w;
        }
#pragma unroll
        for (int kk = 0; kk < 2; ++kk) {
            int m = t + kk * 256;
            int k = m >> 4, j4 = m & 15;
            float4 v = *(const float4*)(W + (size_t)(kc * 32 + k) * ncols + cbase + j4 * 4);
            *(float4*)(bsh + k * 64 + j4 * 4) = v;
        }
        __syncthreads();
#pragma unroll 8
        for (int k = 0; k < 32; ++k) {
            float4 av = *(const float4*)(ash + k * 65 + ti * 4);
            float4 bv = *(const float4*)(bsh + k * 64 + tj * 4);
            acc[0][0] += av.x * bv.x; acc[0][1] += av.x * bv.y;
            acc[0][2] += av.x * bv.z; acc[0][3] += av.x * bv.w;
            acc[1][0] += av.y * bv.x; acc[1][1] += av.y * bv.y;
            acc[1][2] += av.y * bv.z; acc[1][3] += av.y * bv.w;
            acc[2][0] += av.z * bv.x; acc[2][1] += av.z * bv.y;
            acc[2][2] += av.z * bv.z; acc[2][3] += av.z * bv.w;
            acc[3][0] += av.w * bv.x; acc[3][1] += av.w * bv.y;
            acc[3][2] += av.w * bv.z; acc[3][3] += av.w * bv.w;
        }
    }
    if (ct < 12) {
        float* dst = (ct < 4) ? Xq : (ct < 8) ? Xk : Xv;
        int gcol = (ct & 3) * 64 + tj * 4;
        int h = gcol >> 5, dk = gcol & 31;
#pragma unroll
        for (int a = 0; a < 4; ++a) {
            int row = rt * 64 + ti * 4 + a;
            int bb = row >> 8, n = row & 255;
            *(float4*)(dst + ((size_t)(bb * 8 + h) * 256 + n) * 32 + dk) =
                make_float4(acc[a][0], acc[a][1], acc[a][2], acc[a][3]);
        }
    } else {
        int gcol = (ct - 12) * 64 + tj * 4;
#pragma unroll
        for (int a = 0; a < 4; ++a) {
            int row = rt * 64 + ti * 4 + a;
            *(float4*)(T + (size_t)row * 512 + gcol) =
                make_float4(acc[a][0], acc[a][1], acc[a][2], acc[a][3]);
        }
    }
}

// ---------------------------------------------------------------------------
// K4: qk[b,h,i,j] = Xq[b,h,i,:].Xk[b,h,j,:]  — batched tiled GEMM, K=32
// grid = 512, block = 256 (16x16), 4x4 outs
__global__ __launch_bounds__(256) void qk_kernel(
        const float* __restrict__ Xq, const float* __restrict__ Xk,
        float* __restrict__ qk) {
    int x = blockIdx.x;
    int jt = x & 3, it = (x >> 2) & 3, bh = x >> 4;
    int t = threadIdx.x;
    __shared__ float xqsh[32 * 64];
    __shared__ float xksh[32 * 64];
#pragma unroll
    for (int k = 0; k < 2; ++k) {
        int m = t + k * 256;
        int i = m >> 3, dq4 = m & 7;
        float4 v = *(const float4*)(Xq + ((size_t)(bh * 256 + it * 64 + i)) * 32 + dq4 * 4);
        xqsh[(dq4 * 4 + 0) * 64 + i] = v.x;
        xqsh[(dq4 * 4 + 1) * 64 + i] = v.y;
        xqsh[(dq4 * 4 + 2) * 64 + i] = v.z;
        xqsh[(dq4 * 4 + 3) * 64 + i] = v.w;
        float4 u = *(const float4*)(Xk + ((size_t)(bh * 256 + jt * 64 + i)) * 32 + dq4 * 4);
        xksh[(dq4 * 4 + 0) * 64 + i] = u.x;
        xksh[(dq4 * 4 + 1) * 64 + i] = u.y;
        xksh[(dq4 * 4 + 2) * 64 + i] = u.z;
        xksh[(dq4 * 4 + 3) * 64 + i] = u.w;
    }
    __syncthreads();
    int ti = t >> 4, tj = t & 15;
    float acc[4][4] = {{0.f}};
#pragma unroll 8
    for (int dk = 0; dk < 32; ++dk) {
        float4 av = *(const float4*)(xqsh + dk * 64 + ti * 4);
        float4 bv = *(const float4*)(xksh + dk * 64 + tj * 4);
        acc[0][0] += av.x * bv.x; acc[0][1] += av.x * bv.y;
        acc[0][2] += av.x * bv.z; acc[0][3] += av.x * bv.w;
        acc[1][0] += av.y * bv.x; acc[1][1] += av.y * bv.y;
        acc[1][2] += av.y * bv.z; acc[1][3] += av.y * bv.w;
        acc[2][0] += av.z * bv.x; acc[2][1] += av.z * bv.y;
        acc[2][2] += av.z * bv.z; acc[2][3] += av.z * bv.w;
        acc[3][0] += av.w * bv.x; acc[3][1] += av.w * bv.y;
        acc[3][2] += av.w * bv.z; acc[3][3] += av.w * bv.w;
    }
#pragma unroll
    for (int a = 0; a < 4; ++a) {
        int i = it * 64 + ti * 4 + a;
        *(float4*)(qk + ((size_t)(bh * 256 + i)) * 256 + jt * 64 + tj * 4) =
            make_float4(acc[a][0], acc[a][1], acc[a][2], acc[a][3]);
    }
}

// ---------------------------------------------------------------------------
// K5: fused bias + softmax + S per (b,i). grid = 1024, block = 256 (4 waves).
// Bias phase is BARRIER-FREE: each wave owns a 64-j strip, staged through a
// wave-private 4.3 KB LDS buffer in four 16jx64r sub-chunks (1 KB/instr
// coalesced global loads, b128-aligned stride-68 rows). r-quarter partials
// reduced with 2 shfl_xor steps. Tsh staged redundantly per wave (benign
// race) -> no startup barrier. LDS ~28 KB -> 5 blocks/CU.
__global__ __launch_bounds__(256) void biassm_kernel(
        const float* __restrict__ link, const float* __restrict__ Tg,
        const float* __restrict__ qk, const int* __restrict__ mask,
        float* __restrict__ alpha, float* __restrict__ S) {
    int bi = blockIdx.x;
    int b = bi >> 8, i = bi & 255;
    int t = threadIdx.x;
    int w = t >> 6, l = t & 63;
    __shared__ __align__(16) float buf[4 * 1088];  // 17.4 KB; wave-private strips; reused as part[]
    __shared__ __align__(16) float Tsh[512];       // 2 KB
    __shared__ __align__(16) float ashm[2048];     // bias -> alpha [h][j] 8 KB
    __shared__ float redsh[64];

    // per-wave redundant Tsh stage (benign race; no barrier needed)
    {
        const float4* tg4 = (const float4*)(Tg + (size_t)bi * 512);
        float4 t0 = tg4[l * 2];
        float4 t1 = tg4[l * 2 + 1];
        *(float4*)(Tsh + l * 8) = t0;
        *(float4*)(Tsh + l * 8 + 4) = t1;
    }

    // ---- bias, barrier-free: wave w owns j in [w*64, w*64+64) ----
    int j_loc = l >> 2, rq = l & 3;
    float* wbuf = buf + w * 1088;                  // 16 rows x 68 floats
    const float4* link4 = (const float4*)link;
    for (int s = 0; s < 4; ++s) {
        int jb = w * 64 + s * 16;
        size_t base4 = ((size_t)(bi * 256 + jb)) * 16;
#pragma unroll
        for (int k = 0; k < 4; ++k) {
            int m = l + k * 64;                    // f4 idx 0..255 (fully coalesced)
            float4 v = link4[base4 + m];
            *(float4*)(wbuf + (m >> 4) * 68 + (m & 15) * 4) = v;
        }
        float pacc[8] = {0.f, 0.f, 0.f, 0.f, 0.f, 0.f, 0.f, 0.f};
#pragma unroll
        for (int rl4 = 0; rl4 < 4; ++rl4) {
            float4 lv = *(const float4*)(wbuf + j_loc * 68 + rq * 16 + rl4 * 4);
#pragma unroll
            for (int h = 0; h < 8; ++h) {
                float4 tv = *(const float4*)(Tsh + h * 64 + rq * 16 + rl4 * 4);
                pacc[h] += lv.x * tv.x + lv.y * tv.y + lv.z * tv.z + lv.w * tv.w;
            }
        }
#pragma unroll
        for (int h = 0; h < 8; ++h) {
            float v = pacc[h];
            v += __shfl_xor(v, 1);
            v += __shfl_xor(v, 2);
            if (rq == 0) ashm[h * 256 + jb + j_loc] = v;
        }
    }
    __syncthreads();  // first block barrier: all bias done

    // ---- softmax (thread = j) ----
    int j = t;
    float s[8];
#pragma unroll
    for (int h = 0; h < 8; ++h) {
        size_t off = ((size_t)(b * 8 + h) * 256 + i) * 256 + j;
        s[h] = (qk[off] + ashm[h * 256 + j]) * SCALE_;
    }
    if (mask[(b * 256 + i) * 256 + j] == 0) {
#pragma unroll
        for (int h = 0; h < 8; ++h) s[h] = -1e9f;
    }
#pragma unroll
    for (int h = 0; h < 8; ++h) {
        float v = s[h];
        for (int off = 32; off > 0; off >>= 1) v = fmaxf(v, __shfl_xor(v, off));
        if (l == 0) redsh[h * 4 + w] = v;
    }
    __syncthreads();
    float mx[8];
#pragma unroll
    for (int h = 0; h < 8; ++h)
        mx[h] = fmaxf(fmaxf(redsh[h * 4 + 0], redsh[h * 4 + 1]),
                      fmaxf(redsh[h * 4 + 2], redsh[h * 4 + 3]));
    __syncthreads();
#pragma unroll
    for (int h = 0; h < 8; ++h) {
        float e = __expf(s[h] - mx[h]);
        s[h] = e;
        float v = e;
        for (int off = 32; off > 0; off >>= 1) v += __shfl_xor(v, off);
        if (l == 0) redsh[32 + h * 4 + w] = v;
    }
    __syncthreads();
#pragma unroll
    for (int h = 0; h < 8; ++h) {
        float esum = redsh[32 + h * 4 + 0] + redsh[32 + h * 4 + 1] +
                     redsh[32 + h * 4 + 2] + redsh[32 + h * 4 + 3];
        float a = s[h] * (1.f / esum);
        ashm[h * 256 + j] = a;
        alpha[((size_t)(b * 8 + h) * 256 + i) * 256 + j] = a;
    }
    __syncthreads();

    // ---- S (wave w owns j in [64w, 64w+64), lane = r; coalesced, L3-hot) ----
    float* part = buf;  // reuse bias strip buffer (2048 floats needed)
    float pacc2[8] = {0.f, 0.f, 0.f, 0.f, 0.f, 0.f, 0.f, 0.f};
    const float* lp2 = link + ((size_t)(bi * 256 + w * 64)) * 64 + l;
#pragma unroll 4
    for (int j4 = 0; j4 < 16; ++j4) {
        float l0 = lp2[(j4 * 4 + 0) * 64];
        float l1 = lp2[(j4 * 4 + 1) * 64];
        float l2 = lp2[(j4 * 4 + 2) * 64];
        float l3 = lp2[(j4 * 4 + 3) * 64];
#pragma unroll
        for (int h = 0; h < 8; ++h) {
            float4 a = *(const float4*)(ashm + h * 256 + w * 64 + j4 * 4);
            pacc2[h] += a.x * l0 + a.y * l1 + a.z * l2 + a.w * l3;
        }
    }
#pragma unroll
    for (int h = 0; h < 8; ++h) part[w * 512 + h * 64 + l] = pacc2[h];
    __syncthreads();
    for (int hr = t; hr < 512; hr += 256) {
        S[(size_t)bi * 512 + hr] =
            part[hr] + part[512 + hr] + part[1024 + hr] + part[1536 + hr];
    }
}

// ---------------------------------------------------------------------------
// K6: fused Z + output: Z[h][dv] = alpha.Xv + S.Ev, then @Wo + residual -> LN.
// grid = 512 (2 rows each), block = 256.
__global__ __launch_bounds__(256) void zout_kernel(
        const float* __restrict__ alpha, const float* __restrict__ Xv,
        const float* __restrict__ S, const float* __restrict__ Ev,
        const float* __restrict__ Wo, const float* __restrict__ q,
        const float* __restrict__ gamma, const float* __restrict__ beta,
        float* __restrict__ out) {
    int blk = blockIdx.x;
    int row0 = blk * 2;                 // rows row0, row0+1 (same b)
    int b = row0 >> 8;
    int t = threadIdx.x;
    __shared__ float Ssh[2 * 512];      // 4 KB
    __shared__ float ashm[2 * 2048];    // alpha [rr][h][j] 16 KB
    __shared__ float zsh[2 * 256];      // 2 KB
    __shared__ float redsh[16];
    for (int m = t; m < 1024; m += 256)
        Ssh[m] = S[(size_t)(row0 + (m >> 9)) * 512 + (m & 511)];
    for (int m = t; m < 4096; m += 256) {
        int rr = m >> 11, h = (m >> 8) & 7, j = m & 255;
        ashm[m] = alpha[((size_t)(b * 8 + h) * 256 + ((row0 + rr) & 255)) * 256 + j];
    }
    __syncthreads();
    // phase 1: Z for both rows
    {
        int h = t >> 5, dv = t & 31;
        float z0 = 0.f, z1 = 0.f;
        const float* xv = Xv + ((size_t)(b * 8 + h) * 256) * 32 + dv;
#pragma unroll 4
        for (int j = 0; j < 256; ++j) {
            float x = xv[j * 32];
            z0 += ashm[h * 256 + j] * x;
            z1 += ashm[2048 + h * 256 + j] * x;
        }
#pragma unroll 4
        for (int r = 0; r < 64; ++r) {
            float ev = Ev[r * 256 + h * 32 + dv];
            z0 += Ssh[h * 64 + r] * ev;
            z1 += Ssh[512 + h * 64 + r] * ev;
        }
        zsh[t] = z0;
        zsh[256 + t] = z1;
    }
    __syncthreads();
    // phase 2: @Wo + residual + LayerNorm (col = t)
    float a0 = q[(size_t)row0 * 256 + t];
    float a1 = q[(size_t)(row0 + 1) * 256 + t];
    for (int d4 = 0; d4 < 64; ++d4) {
        float w0 = Wo[(d4 * 4 + 0) * 256 + t];
        float w1 = Wo[(d4 * 4 + 1) * 256 + t];
        float w2 = Wo[(d4 * 4 + 2) * 256 + t];
        float w3 = Wo[(d4 * 4 + 3) * 256 + t];
        float4 z0v = *(const float4*)(zsh + d4 * 4);
        float4 z1v = *(const float4*)(zsh + 256 + d4 * 4);
        a0 += z0v.x * w0 + z0v.y * w1 + z0v.z * w2 + z0v.w * w3;
        a1 += z1v.x * w0 + z1v.y * w1 + z1v.z * w2 + z1v.w * w3;
    }
    int lane = t & 63, wv = t >> 6;
    float acc2[2] = {a0, a1};
#pragma unroll
    for (int rr = 0; rr < 2; ++rr) {
        float v = acc2[rr], v2 = acc2[rr] * acc2[rr];
        for (int off = 32; off > 0; off >>= 1) {
            v += __shfl_xor(v, off);
            v2 += __shfl_xor(v2, off);
        }
        if (lane == 0) {
            redsh[rr * 8 + wv] = v;
            redsh[rr * 8 + 4 + wv] = v2;
        }
    }
    __syncthreads();
#pragma unroll
    for (int rr = 0; rr < 2; ++rr) {
        float sum = redsh[rr * 8 + 0] + redsh[rr * 8 + 1] + redsh[rr * 8 + 2] + redsh[rr * 8 + 3];
        float sum2 = redsh[rr * 8 + 4] + redsh[rr * 8 + 5] + redsh[rr * 8 + 6] + redsh[rr * 8 + 7];
        float mu = sum * (1.f / 256.f);
        float var = sum2 * (1.f / 256.f) - mu * mu;
        float dev = acc2[rr] - mu;
        out[(size_t)(row0 + rr) * 256 + t] = dev * rsqrtf(var + EPS_) * gamma[t] + beta[t];
    }
}

// ---------------------------------------------------------------------------
extern "C" void kernel_launch(void* const* d_in, const int* in_sizes, int n_in,
                              void* d_out, int out_size, void* d_ws, size_t ws_size,
                              hipStream_t stream) {
    const float* q     = (const float*)d_in[0];
    const int*   mask  = (const int*)d_in[3];
    const float* link  = (const float*)d_in[4];
    const float* Wq    = (const float*)d_in[5];
    const float* Wk    = (const float*)d_in[6];
    const float* Wr    = (const float*)d_in[7];
    const float* Wv    = (const float*)d_in[8];
    const float* Wvv   = (const float*)d_in[9];
    const float* relE  = (const float*)d_in[10];
    const float* Wo    = (const float*)d_in[11];
    const float* gamma = (const float*)d_in[12];
    const float* beta  = (const float*)d_in[13];

    float* out   = (float*)d_out;
    float* alpha = out + B_ * N_ * D_;      // second output [B,H,N,N]

    float* ws    = (float*)d_ws;
    float* Ek    = ws;                         // 16384
    float* Ev    = Ek + 16384;                 // 16384
    float* Mcat  = Ev + 16384;                 // 131072
    float* Xq    = Mcat + 131072;              // 262144
    float* Xk    = Xq + 262144;                // 262144
    float* Xv    = Xk + 262144;                // 262144
    float* T     = Xv + 262144;                // 524288
    float* qkbuf = T + 524288;                 // 2097152
    float* S     = qkbuf + 2097152;            // 524288  (total ~15.5 MB)

    ekev_kernel<<<128, 256, 0, stream>>>(relE, Wr, Wvv, Ek, Ev);
    mcat_kernel<<<256, 256, 0, stream>>>(Wq, Ek, Mcat);
    projT_kernel<<<320, 256, 0, stream>>>(q, Wq, Wk, Wv, Mcat, Xq, Xk, Xv, T);
    qk_kernel<<<512, 256, 0, stream>>>(Xq, Xk, qkbuf);
    biassm_kernel<<<1024, 256, 0, stream>>>(link, T, qkbuf, mask, alpha, S);
    zout_kernel<<<512, 256, 0, stream>>>(alpha, Xv, S, Ev, Wo, q, gamma, beta, out);
}